// Round 5
// baseline (220.050 us; speedup 1.0000x reference)
//
#include <hip/hip_runtime.h>

// GAT fused v5 = v4 + (a) raw barriers (lgkmcnt-only, no vmcnt drain) so the
// x reg-prefetch stays in flight across the whole tile, (b) LDS overlay
// (sP aliases sX, ws/wd alias sHt) -> 34.3 KB -> 4 blocks/CU, grid 1024.

typedef __attribute__((ext_vector_type(8))) short short8;  // 8 bf16
typedef __attribute__((ext_vector_type(4))) float f32x4;

constexpr int   NTILES    = 8192;
constexpr int   GRID      = 1024;     // 4 blocks/CU * 256 CUs, 8 tiles/block
constexpr float NEG_SLOPE = 0.2f;
constexpr float LN_EPS    = 1e-5f;

__device__ __forceinline__ unsigned short f2bf(float f) {
    unsigned int u = __builtin_bit_cast(unsigned int, f);
    return (unsigned short)((u + 0x7FFFu + ((u >> 16) & 1u)) >> 16);
}
__device__ __forceinline__ unsigned swz256(int row, int bytecol) {
    return (unsigned)(row * 256 + bytecol) ^ (unsigned)((row & 7) << 4);
}
__device__ __forceinline__ unsigned swz128(int row, int bytecol) {
    return (unsigned)(row * 128 + bytecol) ^ (unsigned)((row & 7) << 4);
}

// Workgroup barrier WITHOUT the vmcnt(0) drain __syncthreads would emit:
// lgkmcnt(0) makes this wave's LDS writes visible, s_barrier rendezvous.
// Outstanding global loads/stores stay in flight (T4 mechanism).
#define LBAR() do { asm volatile("s_waitcnt lgkmcnt(0)"); __builtin_amdgcn_s_barrier(); } while (0)

__launch_bounds__(256, 4)
__global__ void gat_mfma5(const float* __restrict__ x,
                          const float* __restrict__ W,
                          const float* __restrict__ a_src,
                          const float* __restrict__ a_dst,
                          const float* __restrict__ gamma,
                          const float* __restrict__ beta,
                          float* __restrict__ out)
{
    // sX: x tile bf16 (swz256), 16 KB. sP (alpha, swz128, 8 KB) OVERLAYS sX —
    // sX is dead after Phase B; S4 at loop end protects the next write of sX.
    __shared__ __align__(16) unsigned short sX [64 * 128];
    __shared__ __align__(16) unsigned short sHt[128 * 64];   // h^T bf16, swz128
    __shared__ __align__(16) float s_src[64];
    __shared__ __align__(16) float s_dst[64];
    __shared__ __align__(16) float s_g[128];
    __shared__ __align__(16) float s_b[128];

    unsigned short* sP   = sX;                 // overlay (first 8 KB)
    float*          s_ws = (float*)sHt;        // overlay: read to regs pre-loop
    float*          s_wd = (float*)sHt + 128;

    const int t    = threadIdx.x;
    const int lane = t & 63;
    const int w    = t >> 6;      // wave 0..3
    const int l15  = lane & 15;
    const int lg   = lane >> 4;   // 0..3

    // ---- one-time: ws = W@a_src, wd = W@a_dst ; gamma/beta ----
    if (t < 128) {
        const float4* W4  = reinterpret_cast<const float4*>(W) + t * 32;
        const float4* as4 = reinterpret_cast<const float4*>(a_src);
        const float4* ad4 = reinterpret_cast<const float4*>(a_dst);
        float ws = 0.f, wd = 0.f;
        for (int n4 = 0; n4 < 32; ++n4) {
            float4 wr = W4[n4], as = as4[n4], ad = ad4[n4];
            ws += wr.x*as.x + wr.y*as.y + wr.z*as.z + wr.w*as.w;
            wd += wr.x*ad.x + wr.y*ad.y + wr.z*ad.z + wr.w*ad.w;
        }
        s_ws[t] = ws; s_wd[t] = wd;
        s_g[t] = gamma[t]; s_b[t] = beta[t];
    }

    // ---- one-time: W B-fragments -> registers (loop-invariant) ----
    short8 wfrag[2][4];   // [nb][kb]
    #pragma unroll
    for (int nb = 0; nb < 2; ++nb) {
        #pragma unroll
        for (int kb = 0; kb < 4; ++kb) {
            const int n = 32 * w + nb * 16 + l15;
            float v[8];
            #pragma unroll
            for (int q = 0; q < 8; ++q)
                v[q] = W[(kb * 32 + lg * 8 + q) * 128 + n];
            uint4 p;
            p.x = (unsigned)f2bf(v[0]) | ((unsigned)f2bf(v[1]) << 16);
            p.y = (unsigned)f2bf(v[2]) | ((unsigned)f2bf(v[3]) << 16);
            p.z = (unsigned)f2bf(v[4]) | ((unsigned)f2bf(v[5]) << 16);
            p.w = (unsigned)f2bf(v[6]) | ((unsigned)f2bf(v[7]) << 16);
            wfrag[nb][kb] = __builtin_bit_cast(short8, p);
        }
    }
    __syncthreads();   // setup visible (once; full drain OK here)

    // per-thread ws/wd slice (regs) — overlay region is free after this + S1
    float wsr[8], wdr[8];
    {
        const int k0 = (t & 15) * 8;
        #pragma unroll
        for (int q = 0; q < 8; ++q) { wsr[q] = s_ws[k0 + q]; wdr[q] = s_wd[k0 + q]; }
    }

    // ---- prologue: load first x tile into regs ----
    float4 px[8];
    {
        const float4* x4 = reinterpret_cast<const float4*>(x + (size_t)blockIdx.x * 8192);
        #pragma unroll
        for (int c = 0; c < 4; ++c) {
            const int idx8 = t + 256 * c;
            px[2*c]   = x4[idx8 * 2];
            px[2*c+1] = x4[idx8 * 2 + 1];
        }
    }

    for (int tile = blockIdx.x; tile < NTILES; tile += GRID) {
        float* ob = out + (size_t)tile * 8192;

        // ---- Phase A: stage x (bf16, swizzled) + f32 scores from px regs ----
        #pragma unroll
        for (int c = 0; c < 4; ++c) {
            const float4 v0 = px[2*c], v1 = px[2*c+1];
            float ps = v0.x*wsr[0] + v0.y*wsr[1] + v0.z*wsr[2] + v0.w*wsr[3]
                     + v1.x*wsr[4] + v1.y*wsr[5] + v1.z*wsr[6] + v1.w*wsr[7];
            float pd = v0.x*wdr[0] + v0.y*wdr[1] + v0.z*wdr[2] + v0.w*wdr[3]
                     + v1.x*wdr[4] + v1.y*wdr[5] + v1.z*wdr[6] + v1.w*wdr[7];
            uint4 pk;
            pk.x = (unsigned)f2bf(v0.x) | ((unsigned)f2bf(v0.y) << 16);
            pk.y = (unsigned)f2bf(v0.z) | ((unsigned)f2bf(v0.w) << 16);
            pk.z = (unsigned)f2bf(v1.x) | ((unsigned)f2bf(v1.y) << 16);
            pk.w = (unsigned)f2bf(v1.z) | ((unsigned)f2bf(v1.w) << 16);
            const int m = (t >> 4) + 16 * c;
            *(uint4*)((char*)sX + swz256(m, (t & 15) * 16)) = pk;
            #pragma unroll
            for (int msk = 1; msk < 16; msk <<= 1) {
                ps += __shfl_xor(ps, msk, 64);
                pd += __shfl_xor(pd, msk, 64);
            }
            if ((t & 15) == 0) { s_src[m] = ps; s_dst[m] = pd; }
        }

        // ---- prefetch next tile's x (px dead now; loads fly across barriers) ----
        if (tile + GRID < NTILES) {
            const float4* xn = reinterpret_cast<const float4*>(x + (size_t)(tile + GRID) * 8192);
            #pragma unroll
            for (int c = 0; c < 4; ++c) {
                const int idx8 = t + 256 * c;
                px[2*c]   = xn[idx8 * 2];
                px[2*c+1] = xn[idx8 * 2 + 1];
            }
        }
        LBAR();   // S1: sX + scores visible

        // ---- Phase B: GEMM1 h = x@W (A from LDS, B from regs) + write h^T ----
        f32x4 acc[4][2];
        #pragma unroll
        for (int mi = 0; mi < 4; ++mi) {
            acc[mi][0] = f32x4{0.f,0.f,0.f,0.f};
            acc[mi][1] = f32x4{0.f,0.f,0.f,0.f};
        }
        #pragma unroll
        for (int kb = 0; kb < 4; ++kb) {
            const int kbyte = kb * 64 + lg * 16;
            #pragma unroll
            for (int mi = 0; mi < 4; ++mi) {
                short8 afr = *(const short8*)((char*)sX + swz256(mi * 16 + l15, kbyte));
                acc[mi][0] = __builtin_amdgcn_mfma_f32_16x16x32_bf16(afr, wfrag[0][kb], acc[mi][0], 0, 0, 0);
                acc[mi][1] = __builtin_amdgcn_mfma_f32_16x16x32_bf16(afr, wfrag[1][kb], acc[mi][1], 0, 0, 0);
            }
        }
        #pragma unroll
        for (int mi = 0; mi < 4; ++mi) {
            const int m0 = mi * 16 + lg * 4;
            #pragma unroll
            for (int nb = 0; nb < 2; ++nb) {
                const int n = 32 * w + nb * 16 + l15;
                uint2 pk;
                pk.x = (unsigned)f2bf(acc[mi][nb][0]) | ((unsigned)f2bf(acc[mi][nb][1]) << 16);
                pk.y = (unsigned)f2bf(acc[mi][nb][2]) | ((unsigned)f2bf(acc[mi][nb][3]) << 16);
                *(uint2*)((char*)sHt + swz128(n, m0 * 2)) = pk;
            }
        }
        LBAR();   // S2: h^T visible; sX dead from here

        // ---- Phase C: softmax -> alpha (bf16, into sP = sX overlay) ----
        {
            const int i = t >> 2, jg = t & 3;
            const float srci = s_src[i];
            float e[16];
            float mx = -1e30f;
            #pragma unroll
            for (int q = 0; q < 16; ++q) {
                float v = srci + s_dst[jg * 16 + q];
                v = (v >= 0.f) ? v : NEG_SLOPE * v;
                e[q] = v;
                mx = fmaxf(mx, v);
            }
            mx = fmaxf(mx, __shfl_xor(mx, 1, 64));
            mx = fmaxf(mx, __shfl_xor(mx, 2, 64));
            float sm = 0.f;
            #pragma unroll
            for (int q = 0; q < 16; ++q) { e[q] = __expf(e[q] - mx); sm += e[q]; }
            sm += __shfl_xor(sm, 1, 64);
            sm += __shfl_xor(sm, 2, 64);
            const float inv = 1.0f / sm;
            unsigned short a_[16];
            #pragma unroll
            for (int q = 0; q < 16; ++q) a_[q] = f2bf(e[q] * inv);
            uint4 pk0, pk1;
            pk0.x = (unsigned)a_[0]  | ((unsigned)a_[1]  << 16);
            pk0.y = (unsigned)a_[2]  | ((unsigned)a_[3]  << 16);
            pk0.z = (unsigned)a_[4]  | ((unsigned)a_[5]  << 16);
            pk0.w = (unsigned)a_[6]  | ((unsigned)a_[7]  << 16);
            pk1.x = (unsigned)a_[8]  | ((unsigned)a_[9]  << 16);
            pk1.y = (unsigned)a_[10] | ((unsigned)a_[11] << 16);
            pk1.z = (unsigned)a_[12] | ((unsigned)a_[13] << 16);
            pk1.w = (unsigned)a_[14] | ((unsigned)a_[15] << 16);
            *(uint4*)((char*)sP + swz128(i, jg * 32))      = pk0;
            *(uint4*)((char*)sP + swz128(i, jg * 32 + 16)) = pk1;
        }
        LBAR();   // S3: alpha visible

        // ---- Phase D: GEMM2 out^T = h^T @ alpha^T + LN + relu + store ----
        f32x4 o[8];
        #pragma unroll
        for (int mi = 0; mi < 8; ++mi) o[mi] = f32x4{0.f,0.f,0.f,0.f};
        #pragma unroll
        for (int kb = 0; kb < 2; ++kb) {
            const int jbyte = kb * 64 + lg * 16;
            short8 bfr = *(const short8*)((char*)sP + swz128(w * 16 + l15, jbyte));
            #pragma unroll
            for (int mi = 0; mi < 8; ++mi) {
                short8 afr = *(const short8*)((char*)sHt + swz128(mi * 16 + l15, jbyte));
                o[mi] = __builtin_amdgcn_mfma_f32_16x16x32_bf16(afr, bfr, o[mi], 0, 0, 0);
            }
        }

        float sm1 = 0.f, sm2 = 0.f;
        #pragma unroll
        for (int mi = 0; mi < 8; ++mi) {
            #pragma unroll
            for (int r = 0; r < 4; ++r) { const float v = o[mi][r]; sm1 += v; sm2 += v * v; }
        }
        sm1 += __shfl_xor(sm1, 16, 64); sm2 += __shfl_xor(sm2, 16, 64);
        sm1 += __shfl_xor(sm1, 32, 64); sm2 += __shfl_xor(sm2, 32, 64);
        const float mu   = sm1 * (1.f / 128.f);
        const float var  = sm2 * (1.f / 128.f) - mu * mu;
        const float rstd = rsqrtf(var + LN_EPS);

        float* orow = ob + (w * 16 + l15) * 128;
        #pragma unroll
        for (int mi = 0; mi < 8; ++mi) {
            const int n0 = mi * 16 + lg * 4;
            const float4 gv = *(const float4*)&s_g[n0];
            const float4 bv = *(const float4*)&s_b[n0];
            float4 vo;
            vo.x = fmaxf((o[mi][0] - mu) * rstd * gv.x + bv.x, 0.f);
            vo.y = fmaxf((o[mi][1] - mu) * rstd * gv.y + bv.y, 0.f);
            vo.z = fmaxf((o[mi][2] - mu) * rstd * gv.z + bv.z, 0.f);
            vo.w = fmaxf((o[mi][3] - mu) * rstd * gv.w + bv.w, 0.f);
            *(float4*)(orow + n0) = vo;
        }
        LBAR();   // S4: all sP reads done before next tile overwrites sX overlay
    }
}

extern "C" void kernel_launch(void* const* d_in, const int* in_sizes, int n_in,
                              void* d_out, int out_size, void* d_ws, size_t ws_size,
                              hipStream_t stream) {
    const float* x   = (const float*)d_in[0];
    const float* W   = (const float*)d_in[1];
    const float* asv = (const float*)d_in[2];
    const float* adv = (const float*)d_in[3];
    const float* gm  = (const float*)d_in[4];
    const float* bt  = (const float*)d_in[5];
    float* out = (float*)d_out;

    hipLaunchKernelGGL(gat_mfma5, dim3(GRID), dim3(256), 0, stream,
                       x, W, asv, adv, gm, bt, out);
}

// Round 6
// 122.392 us; speedup vs baseline: 1.7979x; 1.7979x over previous
//
#include <hip/hip_runtime.h>

// GAT fused v6 = v2's proven envelope (W in LDS, launch_bounds(256,2), 2 blk/CU,
// GRID=512) + verified structural wins: scores folded into staging (from px regs),
// px reg-prefetch across non-draining LBAR barriers, sP overlaid on sX.
// Register budget deliberately ~100 VGPR < 256 cap: NO SPILLS (R4/R5 lesson).

typedef __attribute__((ext_vector_type(8))) short short8;  // 8 bf16
typedef __attribute__((ext_vector_type(4))) float f32x4;

constexpr int   NTILES    = 8192;
constexpr int   GRID      = 512;      // 2 blocks/CU * 256 CUs, 16 tiles/block
constexpr float NEG_SLOPE = 0.2f;
constexpr float LN_EPS    = 1e-5f;

__device__ __forceinline__ unsigned short f2bf(float f) {
    unsigned int u = __builtin_bit_cast(unsigned int, f);
    return (unsigned short)((u + 0x7FFFu + ((u >> 16) & 1u)) >> 16);
}
__device__ __forceinline__ unsigned swz256(int row, int bytecol) {
    return (unsigned)(row * 256 + bytecol) ^ (unsigned)((row & 7) << 4);
}
__device__ __forceinline__ unsigned swz128(int row, int bytecol) {
    return (unsigned)(row * 128 + bytecol) ^ (unsigned)((row & 7) << 4);
}

// Workgroup barrier WITHOUT __syncthreads' vmcnt(0) drain: LDS writes visible
// (lgkmcnt), global loads/stores stay in flight (T4). Correctness-proven in v5.
#define LBAR() do { asm volatile("s_waitcnt lgkmcnt(0)"); __builtin_amdgcn_s_barrier(); } while (0)

__launch_bounds__(256, 2)
__global__ void gat_mfma6(const float* __restrict__ x,
                          const float* __restrict__ W,
                          const float* __restrict__ a_src,
                          const float* __restrict__ a_dst,
                          const float* __restrict__ gamma,
                          const float* __restrict__ beta,
                          float* __restrict__ out)
{
    __shared__ __align__(16) unsigned short sWt[128 * 128]; // W^T bf16, swz256 (32 KB)
    __shared__ __align__(16) unsigned short sX [64 * 128];  // x tile bf16, swz256 (16 KB)
    __shared__ __align__(16) unsigned short sHt[128 * 64];  // h^T bf16, swz128 (16 KB)
    __shared__ __align__(16) float s_src[64];
    __shared__ __align__(16) float s_dst[64];
    __shared__ __align__(16) float s_g[128];
    __shared__ __align__(16) float s_b[128];

    unsigned short* sP   = sX;              // alpha overlays sX (dead after GEMM1)
    float*          s_ws = (float*)sHt;     // setup-only overlay, read to regs pre-loop
    float*          s_wd = (float*)sHt + 128;

    const int t    = threadIdx.x;
    const int lane = t & 63;
    const int w    = t >> 6;      // wave 0..3
    const int l15  = lane & 15;
    const int lg   = lane >> 4;   // 0..3

    // ---- one-time: ws = W@a_src, wd = W@a_dst ; gamma/beta ----
    if (t < 128) {
        const float4* W4  = reinterpret_cast<const float4*>(W) + t * 32;
        const float4* as4 = reinterpret_cast<const float4*>(a_src);
        const float4* ad4 = reinterpret_cast<const float4*>(a_dst);
        float ws = 0.f, wd = 0.f;
        for (int n4 = 0; n4 < 32; ++n4) {
            float4 wr = W4[n4], as = as4[n4], ad = ad4[n4];
            ws += wr.x*as.x + wr.y*as.y + wr.z*as.z + wr.w*as.w;
            wd += wr.x*ad.x + wr.y*ad.y + wr.z*ad.z + wr.w*ad.w;
        }
        s_ws[t] = ws; s_wd[t] = wd;
        s_g[t] = gamma[t]; s_b[t] = beta[t];
    }

    // ---- one-time: stage W^T as bf16 into LDS (v2-proven transpose) ----
    {
        const float4* W4 = reinterpret_cast<const float4*>(W);
        for (int c = 0; c < 16; ++c) {
            int idx4 = t + 256 * c;          // 0..4095
            float4 v = W4[idx4];
            int k  = idx4 >> 5;              // 32 float4 per 128-wide row
            int n0 = (idx4 & 31) << 2;
            *(unsigned short*)((char*)sWt + swz256(n0 + 0, k * 2)) = f2bf(v.x);
            *(unsigned short*)((char*)sWt + swz256(n0 + 1, k * 2)) = f2bf(v.y);
            *(unsigned short*)((char*)sWt + swz256(n0 + 2, k * 2)) = f2bf(v.z);
            *(unsigned short*)((char*)sWt + swz256(n0 + 3, k * 2)) = f2bf(v.w);
        }
    }
    __syncthreads();   // setup visible (one-time; full drain fine)

    // per-thread ws/wd slice to regs; sHt overlay free after S1 of iter 0
    float wsr[8], wdr[8];
    {
        const int k0 = (t & 15) * 8;
        #pragma unroll
        for (int q = 0; q < 8; ++q) { wsr[q] = s_ws[k0 + q]; wdr[q] = s_wd[k0 + q]; }
    }

    // ---- prologue: load first x tile into regs ----
    float4 px[8];
    {
        const float4* x4 = reinterpret_cast<const float4*>(x + (size_t)blockIdx.x * 8192);
        #pragma unroll
        for (int c = 0; c < 4; ++c) {
            const int idx8 = t + 256 * c;
            px[2*c]   = x4[idx8 * 2];
            px[2*c+1] = x4[idx8 * 2 + 1];
        }
    }

    for (int tile = blockIdx.x; tile < NTILES; tile += GRID) {
        float* ob = out + (size_t)tile * 8192;

        // ---- Phase A: stage x (bf16, swizzled) + f32 scores from px regs ----
        #pragma unroll
        for (int c = 0; c < 4; ++c) {
            const float4 v0 = px[2*c], v1 = px[2*c+1];
            float ps = v0.x*wsr[0] + v0.y*wsr[1] + v0.z*wsr[2] + v0.w*wsr[3]
                     + v1.x*wsr[4] + v1.y*wsr[5] + v1.z*wsr[6] + v1.w*wsr[7];
            float pd = v0.x*wdr[0] + v0.y*wdr[1] + v0.z*wdr[2] + v0.w*wdr[3]
                     + v1.x*wdr[4] + v1.y*wdr[5] + v1.z*wdr[6] + v1.w*wdr[7];
            uint4 pk;
            pk.x = (unsigned)f2bf(v0.x) | ((unsigned)f2bf(v0.y) << 16);
            pk.y = (unsigned)f2bf(v0.z) | ((unsigned)f2bf(v0.w) << 16);
            pk.z = (unsigned)f2bf(v1.x) | ((unsigned)f2bf(v1.y) << 16);
            pk.w = (unsigned)f2bf(v1.z) | ((unsigned)f2bf(v1.w) << 16);
            const int m = (t >> 4) + 16 * c;
            *(uint4*)((char*)sX + swz256(m, (t & 15) * 16)) = pk;
            #pragma unroll
            for (int msk = 1; msk < 16; msk <<= 1) {
                ps += __shfl_xor(ps, msk, 64);
                pd += __shfl_xor(pd, msk, 64);
            }
            if ((t & 15) == 0) { s_src[m] = ps; s_dst[m] = pd; }
        }

        // ---- prefetch next tile's x (px dead; loads fly across LBARs) ----
        if (tile + GRID < NTILES) {
            const float4* xn = reinterpret_cast<const float4*>(x + (size_t)(tile + GRID) * 8192);
            #pragma unroll
            for (int c = 0; c < 4; ++c) {
                const int idx8 = t + 256 * c;
                px[2*c]   = xn[idx8 * 2];
                px[2*c+1] = xn[idx8 * 2 + 1];
            }
        }
        LBAR();   // S1: sX + scores visible

        // ---- Phase B: GEMM1 h = x@W (A from sX, B from sWt) + write h^T ----
        f32x4 acc[4][2];
        #pragma unroll
        for (int mi = 0; mi < 4; ++mi) {
            acc[mi][0] = f32x4{0.f,0.f,0.f,0.f};
            acc[mi][1] = f32x4{0.f,0.f,0.f,0.f};
        }
        #pragma unroll
        for (int kb = 0; kb < 4; ++kb) {
            const int kbyte = kb * 64 + lg * 16;
            short8 bfr0 = *(const short8*)((char*)sWt + swz256(32 * w +  0 + l15, kbyte));
            short8 bfr1 = *(const short8*)((char*)sWt + swz256(32 * w + 16 + l15, kbyte));
            #pragma unroll
            for (int mi = 0; mi < 4; ++mi) {
                short8 afr = *(const short8*)((char*)sX + swz256(mi * 16 + l15, kbyte));
                acc[mi][0] = __builtin_amdgcn_mfma_f32_16x16x32_bf16(afr, bfr0, acc[mi][0], 0, 0, 0);
                acc[mi][1] = __builtin_amdgcn_mfma_f32_16x16x32_bf16(afr, bfr1, acc[mi][1], 0, 0, 0);
            }
        }
        #pragma unroll
        for (int mi = 0; mi < 4; ++mi) {
            const int m0 = mi * 16 + lg * 4;
            #pragma unroll
            for (int nb = 0; nb < 2; ++nb) {
                const int n = 32 * w + nb * 16 + l15;
                uint2 pk;
                pk.x = (unsigned)f2bf(acc[mi][nb][0]) | ((unsigned)f2bf(acc[mi][nb][1]) << 16);
                pk.y = (unsigned)f2bf(acc[mi][nb][2]) | ((unsigned)f2bf(acc[mi][nb][3]) << 16);
                *(uint2*)((char*)sHt + swz128(n, m0 * 2)) = pk;
            }
        }
        LBAR();   // S2: h^T visible; sX dead from here

        // ---- Phase C: softmax -> alpha (bf16, into sP = sX overlay) ----
        {
            const int i = t >> 2, jg = t & 3;
            const float srci = s_src[i];
            float e[16];
            float mx = -1e30f;
            #pragma unroll
            for (int q = 0; q < 16; ++q) {
                float v = srci + s_dst[jg * 16 + q];
                v = (v >= 0.f) ? v : NEG_SLOPE * v;
                e[q] = v;
                mx = fmaxf(mx, v);
            }
            mx = fmaxf(mx, __shfl_xor(mx, 1, 64));
            mx = fmaxf(mx, __shfl_xor(mx, 2, 64));
            float sm = 0.f;
            #pragma unroll
            for (int q = 0; q < 16; ++q) { e[q] = __expf(e[q] - mx); sm += e[q]; }
            sm += __shfl_xor(sm, 1, 64);
            sm += __shfl_xor(sm, 2, 64);
            const float inv = 1.0f / sm;
            unsigned short a_[16];
            #pragma unroll
            for (int q = 0; q < 16; ++q) a_[q] = f2bf(e[q] * inv);
            uint4 pk0, pk1;
            pk0.x = (unsigned)a_[0]  | ((unsigned)a_[1]  << 16);
            pk0.y = (unsigned)a_[2]  | ((unsigned)a_[3]  << 16);
            pk0.z = (unsigned)a_[4]  | ((unsigned)a_[5]  << 16);
            pk0.w = (unsigned)a_[6]  | ((unsigned)a_[7]  << 16);
            pk1.x = (unsigned)a_[8]  | ((unsigned)a_[9]  << 16);
            pk1.y = (unsigned)a_[10] | ((unsigned)a_[11] << 16);
            pk1.z = (unsigned)a_[12] | ((unsigned)a_[13] << 16);
            pk1.w = (unsigned)a_[14] | ((unsigned)a_[15] << 16);
            *(uint4*)((char*)sP + swz128(i, jg * 32))      = pk0;
            *(uint4*)((char*)sP + swz128(i, jg * 32 + 16)) = pk1;
        }
        LBAR();   // S3: alpha visible

        // ---- Phase D: GEMM2 out^T = h^T @ alpha^T + LN + relu + store ----
        f32x4 o[8];
        #pragma unroll
        for (int mi = 0; mi < 8; ++mi) o[mi] = f32x4{0.f,0.f,0.f,0.f};
        #pragma unroll
        for (int kb = 0; kb < 2; ++kb) {
            const int jbyte = kb * 64 + lg * 16;
            short8 bfr = *(const short8*)((char*)sP + swz128(w * 16 + l15, jbyte));
            #pragma unroll
            for (int mi = 0; mi < 8; ++mi) {
                short8 afr = *(const short8*)((char*)sHt + swz128(mi * 16 + l15, jbyte));
                o[mi] = __builtin_amdgcn_mfma_f32_16x16x32_bf16(afr, bfr, o[mi], 0, 0, 0);
            }
        }

        float sm1 = 0.f, sm2 = 0.f;
        #pragma unroll
        for (int mi = 0; mi < 8; ++mi) {
            #pragma unroll
            for (int r = 0; r < 4; ++r) { const float v = o[mi][r]; sm1 += v; sm2 += v * v; }
        }
        sm1 += __shfl_xor(sm1, 16, 64); sm2 += __shfl_xor(sm2, 16, 64);
        sm1 += __shfl_xor(sm1, 32, 64); sm2 += __shfl_xor(sm2, 32, 64);
        const float mu   = sm1 * (1.f / 128.f);
        const float var  = sm2 * (1.f / 128.f) - mu * mu;
        const float rstd = rsqrtf(var + LN_EPS);

        float* orow = ob + (w * 16 + l15) * 128;
        #pragma unroll
        for (int mi = 0; mi < 8; ++mi) {
            const int n0 = mi * 16 + lg * 4;
            const float4 gv = *(const float4*)&s_g[n0];
            const float4 bv = *(const float4*)&s_b[n0];
            float4 vo;
            vo.x = fmaxf((o[mi][0] - mu) * rstd * gv.x + bv.x, 0.f);
            vo.y = fmaxf((o[mi][1] - mu) * rstd * gv.y + bv.y, 0.f);
            vo.z = fmaxf((o[mi][2] - mu) * rstd * gv.z + bv.z, 0.f);
            vo.w = fmaxf((o[mi][3] - mu) * rstd * gv.w + bv.w, 0.f);
            *(float4*)(orow + n0) = vo;
        }
        LBAR();   // S4: all sP reads done before next tile's Phase A overwrites sX
    }
}

extern "C" void kernel_launch(void* const* d_in, const int* in_sizes, int n_in,
                              void* d_out, int out_size, void* d_ws, size_t ws_size,
                              hipStream_t stream) {
    const float* x   = (const float*)d_in[0];
    const float* W   = (const float*)d_in[1];
    const float* asv = (const float*)d_in[2];
    const float* adv = (const float*)d_in[3];
    const float* gm  = (const float*)d_in[4];
    const float* bt  = (const float*)d_in[5];
    float* out = (float*)d_out;

    hipLaunchKernelGGL(gat_mfma6, dim3(GRID), dim3(256), 0, stream,
                       x, W, asv, adv, gm, bt, out);
}